// Round 8
// baseline (722.420 us; speedup 1.0000x reference)
//
#include <hip/hip_runtime.h>
#include <math.h>

#define B_ 4
#define L_ 1024
#define D_ 1024
#define H_ 16
#define DH_ 64
#define M_ (B_*L_)   // 4096 rows

typedef _Float16 half8 __attribute__((ext_vector_type(8)));
typedef _Float16 half4 __attribute__((ext_vector_type(4)));
typedef float f32x4 __attribute__((ext_vector_type(4)));

#define MFMA16(a,b,c) __builtin_amdgcn_mfma_f32_16x16x32_f16(a, b, c, 0, 0, 0)

// ---- DPP wave64 reductions (verified passing in R6)
#define DPPF(oldv, x, ctrl, rmask) \
  __int_as_float(__builtin_amdgcn_update_dpp(__float_as_int(oldv), __float_as_int(x), ctrl, rmask, 0xf, false))

__device__ __forceinline__ float wfred_max(float x) {
  x = fmaxf(x, DPPF(-INFINITY, x, 0x111, 0xf));
  x = fmaxf(x, DPPF(-INFINITY, x, 0x112, 0xf));
  x = fmaxf(x, DPPF(-INFINITY, x, 0x114, 0xf));
  x = fmaxf(x, DPPF(-INFINITY, x, 0x118, 0xf));
  x = fmaxf(x, DPPF(-INFINITY, x, 0x142, 0xa));
  x = fmaxf(x, DPPF(-INFINITY, x, 0x143, 0xc));
  return __int_as_float(__builtin_amdgcn_readlane(__float_as_int(x), 63));
}
__device__ __forceinline__ float wfred_sum(float x) {
  x = x + DPPF(0.f, x, 0x111, 0xf);
  x = x + DPPF(0.f, x, 0x112, 0xf);
  x = x + DPPF(0.f, x, 0x114, 0xf);
  x = x + DPPF(0.f, x, 0x118, 0xf);
  x = x + DPPF(0.f, x, 0x142, 0xa);
  x = x + DPPF(0.f, x, 0x143, 0xc);
  return __int_as_float(__builtin_amdgcn_readlane(__float_as_int(x), 63));
}

// ---------------- split kernels: fp32 -> scaled fp16 hi/lo pairs ----------------
__global__ __launch_bounds__(256) void split_x(const float* __restrict__ x,
                                               _Float16* __restrict__ xh,
                                               _Float16* __restrict__ xl) {
  const int i = blockIdx.x * 256 + threadIdx.x;   // 4 floats per thread
  float4 v = ((const float4*)x)[i];
  const float a0 = v.x * 16.f, a1 = v.y * 16.f, a2 = v.z * 16.f, a3 = v.w * 16.f;
  const _Float16 h0 = (_Float16)a0, h1 = (_Float16)a1, h2 = (_Float16)a2, h3 = (_Float16)a3;
  half4 hv, lv;
  hv[0] = h0; hv[1] = h1; hv[2] = h2; hv[3] = h3;
  lv[0] = (_Float16)(a0 - (float)h0);
  lv[1] = (_Float16)(a1 - (float)h1);
  lv[2] = (_Float16)(a2 - (float)h2);
  lv[3] = (_Float16)(a3 - (float)h3);
  ((half4*)xh)[i] = hv;
  ((half4*)xl)[i] = lv;
}

// W[k][n] -> transposed split Wh[n][k], Wl[n][k] (scale 512), via LDS tile.
__global__ __launch_bounds__(256) void split_w4(const float* __restrict__ W0,
                                                const float* __restrict__ W1,
                                                const float* __restrict__ W2,
                                                const float* __restrict__ W3,
                                                _Float16* __restrict__ Whl_base) {
  const int z = blockIdx.z;
  const float* W = (z == 0) ? W0 : (z == 1) ? W1 : (z == 2) ? W2 : W3;
  _Float16* Wh = Whl_base + (size_t)z * 2 * (size_t)(D_ * D_);
  _Float16* Wl = Wh + (size_t)(D_ * D_);
  __shared__ float tile[64][65];
  const int t = threadIdx.x;
  const int tk = blockIdx.x & 15;
  const int tn = blockIdx.x >> 4;
  const int kr = t >> 2, ns = (t & 3) * 16;
  const float* src = W + (size_t)(tk * 64 + kr) * D_ + tn * 64 + ns;
  float4 v0 = ((const float4*)src)[0];
  float4 v1 = ((const float4*)src)[1];
  float4 v2 = ((const float4*)src)[2];
  float4 v3 = ((const float4*)src)[3];
  tile[ns + 0][kr] = v0.x;  tile[ns + 1][kr] = v0.y;  tile[ns + 2][kr] = v0.z;  tile[ns + 3][kr] = v0.w;
  tile[ns + 4][kr] = v1.x;  tile[ns + 5][kr] = v1.y;  tile[ns + 6][kr] = v1.z;  tile[ns + 7][kr] = v1.w;
  tile[ns + 8][kr] = v2.x;  tile[ns + 9][kr] = v2.y;  tile[ns + 10][kr] = v2.z; tile[ns + 11][kr] = v2.w;
  tile[ns + 12][kr] = v3.x; tile[ns + 13][kr] = v3.y; tile[ns + 14][kr] = v3.z; tile[ns + 15][kr] = v3.w;
  __syncthreads();
  const int nr = t >> 2, ks = (t & 3) * 16;
  const float* tr = &tile[nr][ks];
  half8 hv0, hv1, lv0, lv1;
#pragma unroll
  for (int i = 0; i < 8; i++) {
    const float s0 = tr[i] * 512.f;
    const float s1 = tr[i + 8] * 512.f;
    const _Float16 h0 = (_Float16)s0, h1 = (_Float16)s1;
    hv0[i] = h0; hv1[i] = h1;
    lv0[i] = (_Float16)(s0 - (float)h0);
    lv1[i] = (_Float16)(s1 - (float)h1);
  }
  _Float16* dh = Wh + (size_t)(tn * 64 + nr) * D_ + tk * 64 + ks;
  _Float16* dl = Wl + (size_t)(tn * 64 + nr) * D_ + tk * 64 + ks;
  *(half8*)dh = hv0; *(half8*)(dh + 8) = hv1;
  *(half8*)dl = lv0; *(half8*)(dl + 8) = lv1;
}

// ---------------- fp16x3 MFMA GEMM: C = (Ah+Al)(Bh+Bl)/8192 + bias ----------------
__device__ __forceinline__ void gemm_f16x3_body(
    const _Float16* __restrict__ Ah, const _Float16* __restrict__ Al,
    const _Float16* __restrict__ Bh, const _Float16* __restrict__ Bl,
    const float* __restrict__ bias, float* __restrict__ Cf,
    _Float16* __restrict__ Ch, _Float16* __restrict__ Cl, const bool f16out) {
  __shared__ __align__(16) _Float16 sA[2][2][128][32];
  __shared__ __align__(16) _Float16 sB[2][2][128][32];
  const int t = threadIdx.x;
  const int lane = t & 63;
  const int wid = t >> 6;
  const int bm = blockIdx.y * 128;
  const int bn = blockIdx.x * 128;

  const int m0 = t >> 2, sp0 = t & 3;
  const int sl0 = sp0 ^ ((m0 >> 1) & 3);
  const int m1 = m0 + 64;
  const _Float16* gA0h = Ah + (size_t)(bm + m0) * D_ + sl0 * 8;
  const _Float16* gA1h = Ah + (size_t)(bm + m1) * D_ + sl0 * 8;
  const _Float16* gA0l = Al + (size_t)(bm + m0) * D_ + sl0 * 8;
  const _Float16* gA1l = Al + (size_t)(bm + m1) * D_ + sl0 * 8;
  const _Float16* gB0h = Bh + (size_t)(bn + m0) * D_ + sl0 * 8;
  const _Float16* gB1h = Bh + (size_t)(bn + m1) * D_ + sl0 * 8;
  const _Float16* gB0l = Bl + (size_t)(bn + m0) * D_ + sl0 * 8;
  const _Float16* gB1l = Bl + (size_t)(bn + m1) * D_ + sl0 * 8;

  half8 rA0h = *(const half8*)(gA0h);
  half8 rA1h = *(const half8*)(gA1h);
  half8 rA0l = *(const half8*)(gA0l);
  half8 rA1l = *(const half8*)(gA1l);
  half8 rB0h = *(const half8*)(gB0h);
  half8 rB1h = *(const half8*)(gB1h);
  half8 rB0l = *(const half8*)(gB0l);
  half8 rB1l = *(const half8*)(gB1l);
  *(half8*)&sA[0][0][m0][sp0 * 8] = rA0h;
  *(half8*)&sA[0][0][m1][sp0 * 8] = rA1h;
  *(half8*)&sA[0][1][m0][sp0 * 8] = rA0l;
  *(half8*)&sA[0][1][m1][sp0 * 8] = rA1l;
  *(half8*)&sB[0][0][m0][sp0 * 8] = rB0h;
  *(half8*)&sB[0][0][m1][sp0 * 8] = rB1h;
  *(half8*)&sB[0][1][m0][sp0 * 8] = rB0l;
  *(half8*)&sB[0][1][m1][sp0 * 8] = rB1l;
  __syncthreads();

  f32x4 acc[4][4];
#pragma unroll
  for (int i = 0; i < 4; i++)
#pragma unroll
    for (int j = 0; j < 4; j++) acc[i][j] = {0.f, 0.f, 0.f, 0.f};

  const int wr = wid >> 1, wc = wid & 1;
  const int l15 = lane & 15;
  const int soff = ((lane >> 4) ^ ((l15 >> 1) & 3)) * 8;

  int p = 0;
  for (int k0 = 0; k0 < 1024; k0 += 32) {
    const bool more = (k0 + 32) < 1024;
    if (more) {
      const int kk = k0 + 32;
      rA0h = *(const half8*)(gA0h + kk);
      rA1h = *(const half8*)(gA1h + kk);
      rA0l = *(const half8*)(gA0l + kk);
      rA1l = *(const half8*)(gA1l + kk);
      rB0h = *(const half8*)(gB0h + kk);
      rB1h = *(const half8*)(gB1h + kk);
      rB0l = *(const half8*)(gB0l + kk);
      rB1l = *(const half8*)(gB1l + kk);
    }
    half8 bh[4], bl[4];
#pragma unroll
    for (int ni = 0; ni < 4; ni++) {
      const int rb = wc * 64 + ni * 16 + l15;
      bh[ni] = *(const half8*)&sB[p][0][rb][soff];
      bl[ni] = *(const half8*)&sB[p][1][rb][soff];
    }
#pragma unroll
    for (int mi = 0; mi < 4; mi++) {
      const int ra = wr * 64 + mi * 16 + l15;
      const half8 ah = *(const half8*)&sA[p][0][ra][soff];
      const half8 al = *(const half8*)&sA[p][1][ra][soff];
#pragma unroll
      for (int ni = 0; ni < 4; ni++) {
        acc[mi][ni] = MFMA16(ah, bh[ni], acc[mi][ni]);
        acc[mi][ni] = MFMA16(ah, bl[ni], acc[mi][ni]);
        acc[mi][ni] = MFMA16(al, bh[ni], acc[mi][ni]);
      }
    }
    if (more) {
      const int q = p ^ 1;
      *(half8*)&sA[q][0][m0][sp0 * 8] = rA0h;
      *(half8*)&sA[q][0][m1][sp0 * 8] = rA1h;
      *(half8*)&sA[q][1][m0][sp0 * 8] = rA0l;
      *(half8*)&sA[q][1][m1][sp0 * 8] = rA1l;
      *(half8*)&sB[q][0][m0][sp0 * 8] = rB0h;
      *(half8*)&sB[q][0][m1][sp0 * 8] = rB1h;
      *(half8*)&sB[q][1][m0][sp0 * 8] = rB0l;
      *(half8*)&sB[q][1][m1][sp0 * 8] = rB1l;
      __syncthreads();
      p = q;
    }
  }

  // epilogue: C row=(lane>>4)*4+reg, col=lane&15
  const float inv = 1.0f / 8192.0f;
  const int orow = bm + wr * 64 + (lane >> 4) * 4;
  const int ocol = bn + wc * 64 + l15;
#pragma unroll
  for (int ni = 0; ni < 4; ni++) {
    const int col = ocol + ni * 16;
    const float bv = bias[col];
#pragma unroll
    for (int mi = 0; mi < 4; mi++) {
      const f32x4 a = acc[mi][ni];
#pragma unroll
      for (int r = 0; r < 4; r++) {
        const size_t idx = (size_t)(orow + mi * 16 + r) * D_ + col;
        const float val = a[r] * inv + bv;
        if (f16out) {
          const float vs = val * 16.0f;            // scale 16 for attn MFMA
          const _Float16 hh = (_Float16)vs;
          Ch[idx] = hh;
          Cl[idx] = (_Float16)(vs - (float)hh);
        } else {
          Cf[idx] = val;
        }
      }
    }
  }
}

__global__ __launch_bounds__(256, 2) void gemm_qkv_f16(
    const _Float16* __restrict__ xh, const _Float16* __restrict__ xl,
    const _Float16* __restrict__ Whq, const _Float16* __restrict__ Wlq,
    const _Float16* __restrict__ Whk, const _Float16* __restrict__ Wlk,
    const _Float16* __restrict__ Whv, const _Float16* __restrict__ Wlv,
    const float* __restrict__ bq, const float* __restrict__ bk, const float* __restrict__ bv,
    _Float16* __restrict__ qh, _Float16* __restrict__ ql,
    _Float16* __restrict__ kh, _Float16* __restrict__ kl,
    float* __restrict__ vf) {
  const int z = blockIdx.z;
  const _Float16* Bh = (z == 0) ? Whq : (z == 1) ? Whk : Whv;
  const _Float16* Bl = (z == 0) ? Wlq : (z == 1) ? Wlk : Wlv;
  const float* bias = (z == 0) ? bq : (z == 1) ? bk : bv;
  if (z == 2) {
    gemm_f16x3_body(xh, xl, Bh, Bl, bias, vf, nullptr, nullptr, false);
  } else {
    _Float16* Ch = (z == 0) ? qh : kh;
    _Float16* Cl = (z == 0) ? ql : kl;
    gemm_f16x3_body(xh, xl, Bh, Bl, bias, nullptr, Ch, Cl, true);
  }
}

__global__ __launch_bounds__(256, 2) void gemm_out_f16(
    const _Float16* __restrict__ ah, const _Float16* __restrict__ al,
    const _Float16* __restrict__ bh, const _Float16* __restrict__ bl,
    const float* __restrict__ bias, float* __restrict__ C) {
  gemm_f16x3_body(ah, al, bh, bl, bias, C, nullptr, nullptr, false);
}

// ---------------- attention: MFMA QK^T + per-row top-k ----------------
// R8: f32 scores restored (f16 broke selection). 256-thr blocks, 4 waves,
// FOUR q-rows per block (1 row/wave): S[4][1024] f32 + cand = 18 KB LDS ->
// 8 blocks/CU -> 32 waves/CU with fine-grained tails. XCD-aware 1D grid
// swizzle: each XCD gets 8 contiguous (b,h) groups -> per-XCD working set
// ~6 MB (K streamed once, V-gathers L2-warm) instead of 48 MB thrash.
// DPP reductions (R6, verified). Selection numerics identical to R5.
__global__ __launch_bounds__(256, 8) void attn_topk_mfma(
    const _Float16* __restrict__ qh, const _Float16* __restrict__ ql,
    const _Float16* __restrict__ kh, const _Float16* __restrict__ kl,
    const float* __restrict__ vf,
    _Float16* __restrict__ awh, _Float16* __restrict__ awl) {
  __shared__ float S[4][1024];   // 16 KB
  __shared__ int   cidx[4][64];  // 1 KB
  __shared__ float cfe[4][64];   // 1 KB
  const int t = threadIdx.x;
  const int lane = t & 63;
  const int w = t >> 6;              // 0..3, one q-row per wave
  // XCD swizzle: dispatch id -> work id so same-XCD blocks share (b,h)
  const int id = blockIdx.x;               // 0..16383
  const int wk = (id & 7) * 2048 + (id >> 3);
  const int it = wk & 255;                 // i-tile (256 of 4 rows)
  const int bh = wk >> 8;                  // 0..63
  const int h = bh & 15;
  const int b = bh >> 4;
  const int i0 = it * 4;
  const size_t rowbase = (size_t)b * L_;
  const int l15 = lane & 15;
  const int kgrp = lane >> 4;        // 0..3

  // ---- A-frags: rows i0 + (l15&3), duplicated 4x over l15
  half8 Ahf[2], Alf[2];
#pragma unroll
  for (int ks = 0; ks < 2; ks++) {
    const size_t off = (rowbase + i0 + (l15 & 3)) * D_ + h * DH_ + ks * 32 + kgrp * 8;
    Ahf[ks] = *(const half8*)(qh + off);
    Alf[ks] = *(const half8*)(ql + off);
  }

  // ---- QK^T: wave w covers j in [w*256, w*256+256)
  const float sscale = 1.0f / 2048.0f;  // 1/(16*16) * 1/sqrt(64)
  for (int jt = 0; jt < 16; jt++) {
    const int j0 = w * 256 + jt * 16;
    const size_t koff = (rowbase + j0 + l15) * D_ + h * DH_ + kgrp * 8;
    const half8 Bh0 = *(const half8*)(kh + koff);
    const half8 Bh1 = *(const half8*)(kh + koff + 32);
    const half8 Bl0 = *(const half8*)(kl + koff);
    const half8 Bl1 = *(const half8*)(kl + koff + 32);
    f32x4 acc = {0.f, 0.f, 0.f, 0.f};
    acc = MFMA16(Ahf[0], Bh0, acc);
    acc = MFMA16(Ahf[1], Bh1, acc);
    acc = MFMA16(Ahf[0], Bl0, acc);
    acc = MFMA16(Ahf[1], Bl1, acc);
    acc = MFMA16(Alf[0], Bh0, acc);
    acc = MFMA16(Alf[1], Bh1, acc);
    if (kgrp == 0) {                 // all kgrp groups hold identical rows 0..3
#pragma unroll
      for (int r = 0; r < 4; r++)
        S[r][j0 + l15] = acc[r] * sscale;
    }
  }
  __syncthreads();

  // ---- selection: wave w owns row w
  const int row = w;
  float sc[16];
#pragma unroll
  for (int u = 0; u < 16; u++) sc[u] = S[row][u * 64 + lane];

  // ---- max (DPP)
  float mx;
  {
    float m = sc[0];
#pragma unroll
    for (int u = 1; u < 16; u++) m = fmaxf(m, sc[u]);
    mx = wfred_max(m);
  }

  // ---- bisection (window mx-16, 14 iters; exact descent below)
  float lo = mx - 16.f, hi = mx;
  for (int it2 = 0; it2 < 14; ++it2) {
    float mid = 0.5f * (lo + hi);
    int cnt = 0;
#pragma unroll
    for (int u = 0; u < 16; u++) cnt += __popcll(__ballot(sc[u] >= mid));
    if (cnt >= 32) lo = mid; else hi = mid;
  }
  int cabove = 0;
#pragma unroll
  for (int u = 0; u < 16; u++) cabove += __popcll(__ballot(sc[u] >= hi));
  float v31 = hi;
  while (cabove < 32) {
    float nx = -INFINITY;
#pragma unroll
    for (int u = 0; u < 16; u++) nx = fmaxf(nx, (sc[u] < v31) ? sc[u] : -INFINITY);
    nx = wfred_max(nx);
    int ceq = 0;
#pragma unroll
    for (int u = 0; u < 16; u++) ceq += __popcll(__ballot(sc[u] == nx));
    cabove += ceq;
    v31 = nx;
  }
  int c_eq = 0;
#pragma unroll
  for (int u = 0; u < 16; u++) c_eq += __popcll(__ballot(sc[u] == v31));
  const int c_gt = cabove - c_eq;
  const bool span = (cabove > 32);
  const int keep_eq = 32 - c_gt;
  float v32;
  if (span) {
    v32 = v31;
  } else {
    float nx = -INFINITY;
#pragma unroll
    for (int u = 0; u < 16; u++) nx = fmaxf(nx, (sc[u] < v31) ? sc[u] : -INFINITY);
    nx = wfred_max(nx);
    v32 = nx;
  }
  const float tau = 0.5f * (v31 + v32);
  const float invbeta = 166666.67f;   // 1 / 6e-6

  // ---- z (DPP sum; e recomputed from sc)
  float z = 0.f;
#pragma unroll
  for (int u = 0; u < 16; u++) z += __expf(sc[u] - mx);
  z = wfred_sum(z);

  // sigmoid needed only if some score is in the transition band
  bool band = false;
  if (!span) {
    int inband = 0;
#pragma unroll
    for (int u = 0; u < 16; u++)
      inband |= (fabsf(sc[u] - tau) <= 1.81e-4f) ? 1 : 0;
    band = (__ballot(inband) != 0ull);
  }

  const float cutoff = fminf(tau - 1.8e-4f, v31);
  const float* vcol = vf + rowbase * D_ + h * DH_ + lane;
  float o;
  bool fast = false;
  if (!span) {
    // ---- compact candidates (j, fe) into LDS via ballot prefix
    int run = 0;
    float psum = 0.f;
#pragma unroll
    for (int u = 0; u < 16; u++) {
      unsigned long long m = __ballot(sc[u] >= cutoff);
      if (sc[u] >= cutoff) {
        const float eu = __expf(sc[u] - mx);
        float feu;
        if (band) {
          float arg = (sc[u] - tau) * invbeta;
          float fwv = (arg > 30.f) ? 1.f : ((arg < -30.f) ? 0.f : 1.f / (1.f + __expf(-arg)));
          feu = fwv * eu;
        } else {
          feu = (sc[u] > tau) ? eu : 0.f;
        }
        int pos = run + (int)__popcll(m & ((1ull << lane) - 1ull));
        if (pos < 64) { cidx[row][pos] = u * 64 + lane; cfe[row][pos] = feu; }
        psum += feu;
      }
      run += (int)__popcll(m);
    }
    if (run <= 64) {
      fast = true;
      const float Ssum = wfred_sum(psum);
      const int npad = (run + 7) & ~7;
      if (lane < npad - run) { cidx[row][run + lane] = 0; cfe[row][run + lane] = 0.f; }
      float acc = 0.f;
      for (int c = 0; c < npad; c += 8) {
        int jx[8]; float fx[8]; float vv[8];
#pragma unroll
        for (int i = 0; i < 8; i++) { jx[i] = cidx[row][c + i]; fx[i] = cfe[row][c + i]; }
#pragma unroll
        for (int i = 0; i < 8; i++) vv[i] = vcol[(size_t)jx[i] * D_];
#pragma unroll
        for (int i = 0; i < 8; i++) acc = fmaf(fx[i], vv[i], acc);
      }
      o = acc / (Ssum + 1e-8f * z);
    }
  }
  if (!fast) {
    // ---- exact original serial path (span ties / candidate overflow)
    float Ssum = 0.f, acc = 0.f;
    int eq_seen = 0;
    for (int u = 0; u < 16; ++u) {
      unsigned long long mask = __ballot(sc[u] >= cutoff);
      while (mask) {
        int l2 = (int)__builtin_ctzll(mask);
        mask &= mask - 1;
        float s_ = __shfl(sc[u], l2, 64);
        float e_ = __expf(s_ - mx);
        float f_;
        if (span) {
          if (s_ > v31) f_ = 1.f;
          else if (s_ == v31) { f_ = (eq_seen < keep_eq) ? 1.f : 0.f; ++eq_seen; }
          else f_ = 0.f;
        } else {
          float arg = (s_ - tau) * invbeta;
          f_ = (arg > 30.f) ? 1.f : ((arg < -30.f) ? 0.f : 1.f / (1.f + __expf(-arg)));
        }
        float fe_ = f_ * e_;
        Ssum += fe_;
        acc = fmaf(fe_, vcol[(size_t)(u * 64 + l2) * D_], acc);
      }
    }
    o = acc / (Ssum + 1e-8f * z);
  }

  const float os = o * 16.0f;                  // scale 16 for the f16x3 out-GEMM
  const _Float16 oh = (_Float16)os;
  const size_t oidx = (rowbase + i0 + row) * D_ + h * DH_ + lane;
  awh[oidx] = oh;
  awl[oidx] = (_Float16)(os - (float)oh);
}

extern "C" void kernel_launch(void* const* d_in, const int* in_sizes, int n_in,
                              void* d_out, int out_size, void* d_ws, size_t ws_size,
                              hipStream_t stream) {
  const float* x  = (const float*)d_in[0];
  const float* Wq = (const float*)d_in[1];
  const float* bq = (const float*)d_in[2];
  const float* Wk = (const float*)d_in[3];
  const float* bk = (const float*)d_in[4];
  const float* Wv = (const float*)d_in[5];
  const float* bv = (const float*)d_in[6];
  const float* Wo = (const float*)d_in[7];
  const float* bo = (const float*)d_in[8];
  float* out = (float*)d_out;

  const size_t MD = (size_t)M_ * D_;   // 4M elements
  const size_t WD = (size_t)D_ * D_;   // 1M elements
  float* slot0 = (float*)d_ws;
  float* slot1 = slot0 + MD;
  float* vf    = slot1 + MD;
  float* slot3 = vf + MD;
  float* slot4 = slot3 + MD;

  _Float16* qh = (_Float16*)slot0;  _Float16* ql = qh + MD;
  _Float16* kh = (_Float16*)slot1;  _Float16* kl = kh + MD;
  _Float16* xh = (_Float16*)slot3;  _Float16* xl = xh + MD;
  _Float16* awh = xh;               // alias: xh/xl dead after gemm_qkv
  _Float16* awl = xl;
  _Float16* Wsplit = (_Float16*)slot4;   // 8 x WD f16: Whq Wlq Whk Wlk Whv Wlv Who Wlo
  _Float16* Whq = Wsplit;
  _Float16* Wlq = Whq + WD;
  _Float16* Whk = Wlq + WD;
  _Float16* Wlk = Whk + WD;
  _Float16* Whv = Wlk + WD;
  _Float16* Wlv = Whv + WD;
  _Float16* Who = Wlv + WD;
  _Float16* Wlo = Who + WD;

  dim3 b256(256);
  hipLaunchKernelGGL(split_x, dim3(4096), b256, 0, stream, x, xh, xl);
  hipLaunchKernelGGL(split_w4, dim3(256, 1, 4), b256, 0, stream, Wq, Wk, Wv, Wo, Wsplit);
  hipLaunchKernelGGL(gemm_qkv_f16, dim3(8, 32, 3), b256, 0, stream,
                     xh, xl, Whq, Wlq, Whk, Wlk, Whv, Wlv, bq, bk, bv,
                     qh, ql, kh, kl, vf);
  hipLaunchKernelGGL(attn_topk_mfma, dim3(16384), b256, 0, stream,
                     qh, ql, kh, kl, vf, awh, awl);
  hipLaunchKernelGGL(gemm_out_f16, dim3(8, 32), b256, 0, stream,
                     awh, awl, Who, Wlo, bo, out);
}

// Round 9
// 496.465 us; speedup vs baseline: 1.4551x; 1.4551x over previous
//
#include <hip/hip_runtime.h>
#include <math.h>

#define B_ 4
#define L_ 1024
#define D_ 1024
#define H_ 16
#define DH_ 64
#define M_ (B_*L_)   // 4096 rows

typedef _Float16 half8 __attribute__((ext_vector_type(8)));
typedef _Float16 half4 __attribute__((ext_vector_type(4)));
typedef float f32x4 __attribute__((ext_vector_type(4)));

#define MFMA16(a,b,c) __builtin_amdgcn_mfma_f32_16x16x32_f16(a, b, c, 0, 0, 0)

// ---- DPP wave64 reductions (verified passing in R6/R8)
#define DPPF(oldv, x, ctrl, rmask) \
  __int_as_float(__builtin_amdgcn_update_dpp(__float_as_int(oldv), __float_as_int(x), ctrl, rmask, 0xf, false))

__device__ __forceinline__ float wfred_max(float x) {
  x = fmaxf(x, DPPF(-INFINITY, x, 0x111, 0xf));
  x = fmaxf(x, DPPF(-INFINITY, x, 0x112, 0xf));
  x = fmaxf(x, DPPF(-INFINITY, x, 0x114, 0xf));
  x = fmaxf(x, DPPF(-INFINITY, x, 0x118, 0xf));
  x = fmaxf(x, DPPF(-INFINITY, x, 0x142, 0xa));
  x = fmaxf(x, DPPF(-INFINITY, x, 0x143, 0xc));
  return __int_as_float(__builtin_amdgcn_readlane(__float_as_int(x), 63));
}
__device__ __forceinline__ float wfred_sum(float x) {
  x = x + DPPF(0.f, x, 0x111, 0xf);
  x = x + DPPF(0.f, x, 0x112, 0xf);
  x = x + DPPF(0.f, x, 0x114, 0xf);
  x = x + DPPF(0.f, x, 0x118, 0xf);
  x = x + DPPF(0.f, x, 0x142, 0xa);
  x = x + DPPF(0.f, x, 0x143, 0xc);
  return __int_as_float(__builtin_amdgcn_readlane(__float_as_int(x), 63));
}

// ---------------- split kernels: fp32 -> scaled fp16 hi/lo pairs ----------------
__global__ __launch_bounds__(256) void split_x(const float* __restrict__ x,
                                               _Float16* __restrict__ xh,
                                               _Float16* __restrict__ xl) {
  const int i = blockIdx.x * 256 + threadIdx.x;   // 4 floats per thread
  float4 v = ((const float4*)x)[i];
  const float a0 = v.x * 16.f, a1 = v.y * 16.f, a2 = v.z * 16.f, a3 = v.w * 16.f;
  const _Float16 h0 = (_Float16)a0, h1 = (_Float16)a1, h2 = (_Float16)a2, h3 = (_Float16)a3;
  half4 hv, lv;
  hv[0] = h0; hv[1] = h1; hv[2] = h2; hv[3] = h3;
  lv[0] = (_Float16)(a0 - (float)h0);
  lv[1] = (_Float16)(a1 - (float)h1);
  lv[2] = (_Float16)(a2 - (float)h2);
  lv[3] = (_Float16)(a3 - (float)h3);
  ((half4*)xh)[i] = hv;
  ((half4*)xl)[i] = lv;
}

// W[k][n] -> transposed split Wh[n][k], Wl[n][k] (scale 512), via LDS tile.
__global__ __launch_bounds__(256) void split_w4(const float* __restrict__ W0,
                                                const float* __restrict__ W1,
                                                const float* __restrict__ W2,
                                                const float* __restrict__ W3,
                                                _Float16* __restrict__ Whl_base) {
  const int z = blockIdx.z;
  const float* W = (z == 0) ? W0 : (z == 1) ? W1 : (z == 2) ? W2 : W3;
  _Float16* Wh = Whl_base + (size_t)z * 2 * (size_t)(D_ * D_);
  _Float16* Wl = Wh + (size_t)(D_ * D_);
  __shared__ float tile[64][65];
  const int t = threadIdx.x;
  const int tk = blockIdx.x & 15;
  const int tn = blockIdx.x >> 4;
  const int kr = t >> 2, ns = (t & 3) * 16;
  const float* src = W + (size_t)(tk * 64 + kr) * D_ + tn * 64 + ns;
  float4 v0 = ((const float4*)src)[0];
  float4 v1 = ((const float4*)src)[1];
  float4 v2 = ((const float4*)src)[2];
  float4 v3 = ((const float4*)src)[3];
  tile[ns + 0][kr] = v0.x;  tile[ns + 1][kr] = v0.y;  tile[ns + 2][kr] = v0.z;  tile[ns + 3][kr] = v0.w;
  tile[ns + 4][kr] = v1.x;  tile[ns + 5][kr] = v1.y;  tile[ns + 6][kr] = v1.z;  tile[ns + 7][kr] = v1.w;
  tile[ns + 8][kr] = v2.x;  tile[ns + 9][kr] = v2.y;  tile[ns + 10][kr] = v2.z; tile[ns + 11][kr] = v2.w;
  tile[ns + 12][kr] = v3.x; tile[ns + 13][kr] = v3.y; tile[ns + 14][kr] = v3.z; tile[ns + 15][kr] = v3.w;
  __syncthreads();
  const int nr = t >> 2, ks = (t & 3) * 16;
  const float* tr = &tile[nr][ks];
  half8 hv0, hv1, lv0, lv1;
#pragma unroll
  for (int i = 0; i < 8; i++) {
    const float s0 = tr[i] * 512.f;
    const float s1 = tr[i + 8] * 512.f;
    const _Float16 h0 = (_Float16)s0, h1 = (_Float16)s1;
    hv0[i] = h0; hv1[i] = h1;
    lv0[i] = (_Float16)(s0 - (float)h0);
    lv1[i] = (_Float16)(s1 - (float)h1);
  }
  _Float16* dh = Wh + (size_t)(tn * 64 + nr) * D_ + tk * 64 + ks;
  _Float16* dl = Wl + (size_t)(tn * 64 + nr) * D_ + tk * 64 + ks;
  *(half8*)dh = hv0; *(half8*)(dh + 8) = hv1;
  *(half8*)dl = lv0; *(half8*)(dl + 8) = lv1;
}

// ---------------- fp16x3 MFMA GEMM: C = (Ah+Al)(Bh+Bl)/8192 + bias ----------------
__device__ __forceinline__ void gemm_f16x3_body(
    const _Float16* __restrict__ Ah, const _Float16* __restrict__ Al,
    const _Float16* __restrict__ Bh, const _Float16* __restrict__ Bl,
    const float* __restrict__ bias, float* __restrict__ Cf,
    _Float16* __restrict__ Ch, _Float16* __restrict__ Cl, const bool f16out) {
  __shared__ __align__(16) _Float16 sA[2][2][128][32];
  __shared__ __align__(16) _Float16 sB[2][2][128][32];
  const int t = threadIdx.x;
  const int lane = t & 63;
  const int wid = t >> 6;
  const int bm = blockIdx.y * 128;
  const int bn = blockIdx.x * 128;

  const int m0 = t >> 2, sp0 = t & 3;
  const int sl0 = sp0 ^ ((m0 >> 1) & 3);
  const int m1 = m0 + 64;
  const _Float16* gA0h = Ah + (size_t)(bm + m0) * D_ + sl0 * 8;
  const _Float16* gA1h = Ah + (size_t)(bm + m1) * D_ + sl0 * 8;
  const _Float16* gA0l = Al + (size_t)(bm + m0) * D_ + sl0 * 8;
  const _Float16* gA1l = Al + (size_t)(bm + m1) * D_ + sl0 * 8;
  const _Float16* gB0h = Bh + (size_t)(bn + m0) * D_ + sl0 * 8;
  const _Float16* gB1h = Bh + (size_t)(bn + m1) * D_ + sl0 * 8;
  const _Float16* gB0l = Bl + (size_t)(bn + m0) * D_ + sl0 * 8;
  const _Float16* gB1l = Bl + (size_t)(bn + m1) * D_ + sl0 * 8;

  half8 rA0h = *(const half8*)(gA0h);
  half8 rA1h = *(const half8*)(gA1h);
  half8 rA0l = *(const half8*)(gA0l);
  half8 rA1l = *(const half8*)(gA1l);
  half8 rB0h = *(const half8*)(gB0h);
  half8 rB1h = *(const half8*)(gB1h);
  half8 rB0l = *(const half8*)(gB0l);
  half8 rB1l = *(const half8*)(gB1l);
  *(half8*)&sA[0][0][m0][sp0 * 8] = rA0h;
  *(half8*)&sA[0][0][m1][sp0 * 8] = rA1h;
  *(half8*)&sA[0][1][m0][sp0 * 8] = rA0l;
  *(half8*)&sA[0][1][m1][sp0 * 8] = rA1l;
  *(half8*)&sB[0][0][m0][sp0 * 8] = rB0h;
  *(half8*)&sB[0][0][m1][sp0 * 8] = rB1h;
  *(half8*)&sB[0][1][m0][sp0 * 8] = rB0l;
  *(half8*)&sB[0][1][m1][sp0 * 8] = rB1l;
  __syncthreads();

  f32x4 acc[4][4];
#pragma unroll
  for (int i = 0; i < 4; i++)
#pragma unroll
    for (int j = 0; j < 4; j++) acc[i][j] = {0.f, 0.f, 0.f, 0.f};

  const int wr = wid >> 1, wc = wid & 1;
  const int l15 = lane & 15;
  const int soff = ((lane >> 4) ^ ((l15 >> 1) & 3)) * 8;

  int p = 0;
  for (int k0 = 0; k0 < 1024; k0 += 32) {
    const bool more = (k0 + 32) < 1024;
    if (more) {
      const int kk = k0 + 32;
      rA0h = *(const half8*)(gA0h + kk);
      rA1h = *(const half8*)(gA1h + kk);
      rA0l = *(const half8*)(gA0l + kk);
      rA1l = *(const half8*)(gA1l + kk);
      rB0h = *(const half8*)(gB0h + kk);
      rB1h = *(const half8*)(gB1h + kk);
      rB0l = *(const half8*)(gB0l + kk);
      rB1l = *(const half8*)(gB1l + kk);
    }
    half8 bh[4], bl[4];
#pragma unroll
    for (int ni = 0; ni < 4; ni++) {
      const int rb = wc * 64 + ni * 16 + l15;
      bh[ni] = *(const half8*)&sB[p][0][rb][soff];
      bl[ni] = *(const half8*)&sB[p][1][rb][soff];
    }
#pragma unroll
    for (int mi = 0; mi < 4; mi++) {
      const int ra = wr * 64 + mi * 16 + l15;
      const half8 ah = *(const half8*)&sA[p][0][ra][soff];
      const half8 al = *(const half8*)&sA[p][1][ra][soff];
#pragma unroll
      for (int ni = 0; ni < 4; ni++) {
        acc[mi][ni] = MFMA16(ah, bh[ni], acc[mi][ni]);
        acc[mi][ni] = MFMA16(ah, bl[ni], acc[mi][ni]);
        acc[mi][ni] = MFMA16(al, bh[ni], acc[mi][ni]);
      }
    }
    if (more) {
      const int q = p ^ 1;
      *(half8*)&sA[q][0][m0][sp0 * 8] = rA0h;
      *(half8*)&sA[q][0][m1][sp0 * 8] = rA1h;
      *(half8*)&sA[q][1][m0][sp0 * 8] = rA0l;
      *(half8*)&sA[q][1][m1][sp0 * 8] = rA1l;
      *(half8*)&sB[q][0][m0][sp0 * 8] = rB0h;
      *(half8*)&sB[q][0][m1][sp0 * 8] = rB1h;
      *(half8*)&sB[q][1][m0][sp0 * 8] = rB0l;
      *(half8*)&sB[q][1][m1][sp0 * 8] = rB1l;
      __syncthreads();
      p = q;
    }
  }

  // epilogue: C row=(lane>>4)*4+reg, col=lane&15
  const float inv = 1.0f / 8192.0f;
  const int orow = bm + wr * 64 + (lane >> 4) * 4;
  const int ocol = bn + wc * 64 + l15;
#pragma unroll
  for (int ni = 0; ni < 4; ni++) {
    const int col = ocol + ni * 16;
    const float bv = bias[col];
#pragma unroll
    for (int mi = 0; mi < 4; mi++) {
      const f32x4 a = acc[mi][ni];
#pragma unroll
      for (int r = 0; r < 4; r++) {
        const size_t idx = (size_t)(orow + mi * 16 + r) * D_ + col;
        const float val = a[r] * inv + bv;
        if (f16out) {
          const float vs = val * 16.0f;            // scale 16 for attn MFMA
          const _Float16 hh = (_Float16)vs;
          Ch[idx] = hh;
          Cl[idx] = (_Float16)(vs - (float)hh);
        } else {
          Cf[idx] = val;
        }
      }
    }
  }
}

__global__ __launch_bounds__(256, 2) void gemm_qkv_f16(
    const _Float16* __restrict__ xh, const _Float16* __restrict__ xl,
    const _Float16* __restrict__ Whq, const _Float16* __restrict__ Wlq,
    const _Float16* __restrict__ Whk, const _Float16* __restrict__ Wlk,
    const _Float16* __restrict__ Whv, const _Float16* __restrict__ Wlv,
    const float* __restrict__ bq, const float* __restrict__ bk, const float* __restrict__ bv,
    _Float16* __restrict__ qh, _Float16* __restrict__ ql,
    _Float16* __restrict__ kh, _Float16* __restrict__ kl,
    float* __restrict__ vf) {
  const int z = blockIdx.z;
  const _Float16* Bh = (z == 0) ? Whq : (z == 1) ? Whk : Whv;
  const _Float16* Bl = (z == 0) ? Wlq : (z == 1) ? Wlk : Wlv;
  const float* bias = (z == 0) ? bq : (z == 1) ? bk : bv;
  if (z == 2) {
    gemm_f16x3_body(xh, xl, Bh, Bl, bias, vf, nullptr, nullptr, false);
  } else {
    _Float16* Ch = (z == 0) ? qh : kh;
    _Float16* Cl = (z == 0) ? ql : kl;
    gemm_f16x3_body(xh, xl, Bh, Bl, bias, nullptr, Ch, Cl, true);
  }
}

__global__ __launch_bounds__(256, 2) void gemm_out_f16(
    const _Float16* __restrict__ ah, const _Float16* __restrict__ al,
    const _Float16* __restrict__ bh, const _Float16* __restrict__ bl,
    const float* __restrict__ bias, float* __restrict__ C) {
  gemm_f16x3_body(ah, al, bh, bl, bias, C, nullptr, nullptr, false);
}

// ---------------- attention: MFMA QK^T + per-row top-k ----------------
// R9 = R5 structure (verified 311us: 512thr/8 waves/8 rows per block, 1 row
// per wave, 8 jt iters/wave) + DPP reductions (R6-verified) + XCD grid
// swizzle (R8-verified: FETCH 136->25MB). f32 swizzled scores (f16 broke
// selection in R7; R8's 4-row layout doubled QK^T work -- both reverted).
#define SSWZ(row) (((row) & 7) << 2)

__global__ __launch_bounds__(512, 4) void attn_topk_mfma(
    const _Float16* __restrict__ qh, const _Float16* __restrict__ ql,
    const _Float16* __restrict__ kh, const _Float16* __restrict__ kl,
    const float* __restrict__ vf,
    _Float16* __restrict__ awh, _Float16* __restrict__ awl) {
  __shared__ float S[8][1024];   // 32 KB
  __shared__ int   cidx[8][64];  // 2 KB
  __shared__ float cfe[8][64];   // 2 KB
  const int t = threadIdx.x;
  const int lane = t & 63;
  const int w = t >> 6;              // 0..7, one q-row per wave
  // XCD swizzle: 8192 blocks; XCD k (= id%8) gets bh in [8k, 8k+8)
  const int id = blockIdx.x;
  const int wk = (id & 7) * 1024 + (id >> 3);
  const int it = wk & 127;           // i-tile of 8 rows
  const int bh = wk >> 7;            // 0..63
  const int h = bh & 15;
  const int b = bh >> 4;
  const int i0 = it * 8;
  const size_t rowbase = (size_t)b * L_;
  const int l15 = lane & 15;
  const int kgrp = lane >> 4;        // 0..3

  // ---- A-frags: rows i0 + (l15&7), duplicated over l15>=8
  half8 Ahf[2], Alf[2];
#pragma unroll
  for (int ks = 0; ks < 2; ks++) {
    const size_t off = (rowbase + i0 + (l15 & 7)) * D_ + h * DH_ + ks * 32 + kgrp * 8;
    Ahf[ks] = *(const half8*)(qh + off);
    Alf[ks] = *(const half8*)(ql + off);
  }

  // ---- QK^T: wave w covers j in [w*128, w*128+128)
  const float sscale = 1.0f / 2048.0f;  // 1/(16*16) * 1/sqrt(64)
  for (int jt = 0; jt < 8; jt++) {
    const int j0 = w * 128 + jt * 16;
    const size_t koff = (rowbase + j0 + l15) * D_ + h * DH_ + kgrp * 8;
    const half8 Bh0 = *(const half8*)(kh + koff);
    const half8 Bh1 = *(const half8*)(kh + koff + 32);
    const half8 Bl0 = *(const half8*)(kl + koff);
    const half8 Bl1 = *(const half8*)(kl + koff + 32);
    f32x4 acc = {0.f, 0.f, 0.f, 0.f};
    acc = MFMA16(Ahf[0], Bh0, acc);
    acc = MFMA16(Ahf[1], Bh1, acc);
    acc = MFMA16(Ahf[0], Bl0, acc);
    acc = MFMA16(Ahf[1], Bl1, acc);
    acc = MFMA16(Alf[0], Bh0, acc);
    acc = MFMA16(Alf[1], Bh1, acc);
    if (kgrp < 2) {
      const int srow = kgrp * 4;     // rows srow..srow+3 valid (0..7)
#pragma unroll
      for (int r = 0; r < 4; r++)
        S[srow + r][(j0 + l15) ^ SSWZ(srow + r)] = acc[r] * sscale;
    }
  }
  __syncthreads();

  // ---- selection: wave w owns row w
  const int row = w;
  const int swz = SSWZ(row);
  float sc[16];
#pragma unroll
  for (int u = 0; u < 16; u++) sc[u] = S[row][(u * 64 + lane) ^ swz];

  // ---- max (DPP)
  float mx;
  {
    float m = sc[0];
#pragma unroll
    for (int u = 1; u < 16; u++) m = fmaxf(m, sc[u]);
    mx = wfred_max(m);
  }

  // ---- bisection (window mx-16, 14 iters; exact descent below)
  float lo = mx - 16.f, hi = mx;
  for (int it2 = 0; it2 < 14; ++it2) {
    float mid = 0.5f * (lo + hi);
    int cnt = 0;
#pragma unroll
    for (int u = 0; u < 16; u++) cnt += __popcll(__ballot(sc[u] >= mid));
    if (cnt >= 32) lo = mid; else hi = mid;
  }
  int cabove = 0;
#pragma unroll
  for (int u = 0; u < 16; u++) cabove += __popcll(__ballot(sc[u] >= hi));
  float v31 = hi;
  while (cabove < 32) {
    float nx = -INFINITY;
#pragma unroll
    for (int u = 0; u < 16; u++) nx = fmaxf(nx, (sc[u] < v31) ? sc[u] : -INFINITY);
    nx = wfred_max(nx);
    int ceq = 0;
#pragma unroll
    for (int u = 0; u < 16; u++) ceq += __popcll(__ballot(sc[u] == nx));
    cabove += ceq;
    v31 = nx;
  }
  int c_eq = 0;
#pragma unroll
  for (int u = 0; u < 16; u++) c_eq += __popcll(__ballot(sc[u] == v31));
  const int c_gt = cabove - c_eq;
  const bool span = (cabove > 32);
  const int keep_eq = 32 - c_gt;
  float v32;
  if (span) {
    v32 = v31;
  } else {
    float nx = -INFINITY;
#pragma unroll
    for (int u = 0; u < 16; u++) nx = fmaxf(nx, (sc[u] < v31) ? sc[u] : -INFINITY);
    nx = wfred_max(nx);
    v32 = nx;
  }
  const float tau = 0.5f * (v31 + v32);
  const float invbeta = 166666.67f;   // 1 / 6e-6

  // ---- z (DPP sum; e recomputed from sc)
  float z = 0.f;
#pragma unroll
  for (int u = 0; u < 16; u++) z += __expf(sc[u] - mx);
  z = wfred_sum(z);

  // sigmoid needed only if some score is in the transition band
  bool band = false;
  if (!span) {
    int inband = 0;
#pragma unroll
    for (int u = 0; u < 16; u++)
      inband |= (fabsf(sc[u] - tau) <= 1.81e-4f) ? 1 : 0;
    band = (__ballot(inband) != 0ull);
  }

  const float cutoff = fminf(tau - 1.8e-4f, v31);
  const float* vcol = vf + rowbase * D_ + h * DH_ + lane;
  float o;
  bool fast = false;
  if (!span) {
    // ---- compact candidates (j, fe) into LDS via ballot prefix
    int run = 0;
    float psum = 0.f;
#pragma unroll
    for (int u = 0; u < 16; u++) {
      unsigned long long m = __ballot(sc[u] >= cutoff);
      if (sc[u] >= cutoff) {
        const float eu = __expf(sc[u] - mx);
        float feu;
        if (band) {
          float arg = (sc[u] - tau) * invbeta;
          float fwv = (arg > 30.f) ? 1.f : ((arg < -30.f) ? 0.f : 1.f / (1.f + __expf(-arg)));
          feu = fwv * eu;
        } else {
          feu = (sc[u] > tau) ? eu : 0.f;
        }
        int pos = run + (int)__popcll(m & ((1ull << lane) - 1ull));
        if (pos < 64) { cidx[row][pos] = u * 64 + lane; cfe[row][pos] = feu; }
        psum += feu;
      }
      run += (int)__popcll(m);
    }
    if (run <= 64) {
      fast = true;
      const float Ssum = wfred_sum(psum);
      const int npad = (run + 7) & ~7;
      if (lane < npad - run) { cidx[row][run + lane] = 0; cfe[row][run + lane] = 0.f; }
      float acc = 0.f;
      for (int c = 0; c < npad; c += 8) {
        int jx[8]; float fx[8]; float vv[8];
#pragma unroll
        for (int i = 0; i < 8; i++) { jx[i] = cidx[row][c + i]; fx[i] = cfe[row][c + i]; }
#pragma unroll
        for (int i = 0; i < 8; i++) vv[i] = vcol[(size_t)jx[i] * D_];
#pragma unroll
        for (int i = 0; i < 8; i++) acc = fmaf(fx[i], vv[i], acc);
      }
      o = acc / (Ssum + 1e-8f * z);
    }
  }
  if (!fast) {
    // ---- exact original serial path (span ties / candidate overflow)
    float Ssum = 0.f, acc = 0.f;
    int eq_seen = 0;
    for (int u = 0; u < 16; ++u) {
      unsigned long long mask = __ballot(sc[u] >= cutoff);
      while (mask) {
        int l2 = (int)__builtin_ctzll(mask);
        mask &= mask - 1;
        float s_ = __shfl(sc[u], l2, 64);
        float e_ = __expf(s_ - mx);
        float f_;
        if (span) {
          if (s_ > v31) f_ = 1.f;
          else if (s_ == v31) { f_ = (eq_seen < keep_eq) ? 1.f : 0.f; ++eq_seen; }
          else f_ = 0.f;
        } else {
          float arg = (s_ - tau) * invbeta;
          f_ = (arg > 30.f) ? 1.f : ((arg < -30.f) ? 0.f : 1.f / (1.f + __expf(-arg)));
        }
        float fe_ = f_ * e_;
        Ssum += fe_;
        acc = fmaf(fe_, vcol[(size_t)(u * 64 + l2) * D_], acc);
      }
    }
    o = acc / (Ssum + 1e-8f * z);
  }

  const float os = o * 16.0f;                  // scale 16 for the f16x3 out-GEMM
  const _Float16 oh = (_Float16)os;
  const size_t oidx = (rowbase + i0 + row) * D_ + h * DH_ + lane;
  awh[oidx] = oh;
  awl[oidx] = (_Float16)(os - (float)oh);
}

extern "C" void kernel_launch(void* const* d_in, const int* in_sizes, int n_in,
                              void* d_out, int out_size, void* d_ws, size_t ws_size,
                              hipStream_t stream) {
  const float* x  = (const float*)d_in[0];
  const float* Wq = (const float*)d_in[1];
  const float* bq = (const float*)d_in[2];
  const float* Wk = (const float*)d_in[3];
  const float* bk = (const float*)d_in[4];
  const float* Wv = (const float*)d_in[5];
  const float* bv = (const float*)d_in[6];
  const float* Wo = (const float*)d_in[7];
  const float* bo = (const float*)d_in[8];
  float* out = (float*)d_out;

  const size_t MD = (size_t)M_ * D_;   // 4M elements
  const size_t WD = (size_t)D_ * D_;   // 1M elements
  float* slot0 = (float*)d_ws;
  float* slot1 = slot0 + MD;
  float* vf    = slot1 + MD;
  float* slot3 = vf + MD;
  float* slot4 = slot3 + MD;

  _Float16* qh = (_Float16*)slot0;  _Float16* ql = qh + MD;
  _Float16* kh = (_Float16*)slot1;  _Float16* kl = kh + MD;
  _Float16* xh = (_Float16*)slot3;  _Float16* xl = xh + MD;
  _Float16* awh = xh;               // alias: xh/xl dead after gemm_qkv
  _Float16* awl = xl;
  _Float16* Wsplit = (_Float16*)slot4;   // 8 x WD f16: Whq Wlq Whk Wlk Whv Wlv Who Wlo
  _Float16* Whq = Wsplit;
  _Float16* Wlq = Whq + WD;
  _Float16* Whk = Wlq + WD;
  _Float16* Wlk = Whk + WD;
  _Float16* Whv = Wlk + WD;
  _Float16* Wlv = Whv + WD;
  _Float16* Who = Wlv + WD;
  _Float16* Wlo = Who + WD;

  dim3 b256(256);
  hipLaunchKernelGGL(split_x, dim3(4096), b256, 0, stream, x, xh, xl);
  hipLaunchKernelGGL(split_w4, dim3(256, 1, 4), b256, 0, stream, Wq, Wk, Wv, Wo, Wsplit);
  hipLaunchKernelGGL(gemm_qkv_f16, dim3(8, 32, 3), b256, 0, stream,
                     xh, xl, Whq, Wlq, Whk, Wlk, Whv, Wlv, bq, bk, bv,
                     qh, ql, kh, kl, vf);
  hipLaunchKernelGGL(attn_topk_mfma, dim3(8192), dim3(512), 0, stream,
                     qh, ql, kh, kl, vf, awh, awl);
  hipLaunchKernelGGL(gemm_out_f16, dim3(8, 32), b256, 0, stream,
                     awh, awl, Who, Wlo, bo, out);
}

// Round 10
// 495.963 us; speedup vs baseline: 1.4566x; 1.0010x over previous
//
#include <hip/hip_runtime.h>
#include <math.h>

#define B_ 4
#define L_ 1024
#define D_ 1024
#define H_ 16
#define DH_ 64
#define M_ (B_*L_)   // 4096 rows

typedef _Float16 half8 __attribute__((ext_vector_type(8)));
typedef _Float16 half4 __attribute__((ext_vector_type(4)));
typedef float f32x4 __attribute__((ext_vector_type(4)));

#define MFMA16(a,b,c) __builtin_amdgcn_mfma_f32_16x16x32_f16(a, b, c, 0, 0, 0)

// ---- async global->LDS 16B DMA. LDS dest must be wave-uniform base; HW adds
// lane*16. Generic LDS pointer low 32 bits == LDS offset on AMDGPU, so the
// uintptr_t truncation yields the AS3 address (CK's cast pattern).
__device__ __forceinline__ void glds16(const void* g, const void* s) {
  __builtin_amdgcn_global_load_lds(
      (const __attribute__((address_space(1))) uint32_t*)g,
      (__attribute__((address_space(3))) uint32_t*)(uintptr_t)s,
      16, 0, 0);
}

// ---- DPP wave64 reductions (verified passing R6/R8/R9)
#define DPPF(oldv, x, ctrl, rmask) \
  __int_as_float(__builtin_amdgcn_update_dpp(__float_as_int(oldv), __float_as_int(x), ctrl, rmask, 0xf, false))

__device__ __forceinline__ float wfred_max(float x) {
  x = fmaxf(x, DPPF(-INFINITY, x, 0x111, 0xf));
  x = fmaxf(x, DPPF(-INFINITY, x, 0x112, 0xf));
  x = fmaxf(x, DPPF(-INFINITY, x, 0x114, 0xf));
  x = fmaxf(x, DPPF(-INFINITY, x, 0x118, 0xf));
  x = fmaxf(x, DPPF(-INFINITY, x, 0x142, 0xa));
  x = fmaxf(x, DPPF(-INFINITY, x, 0x143, 0xc));
  return __int_as_float(__builtin_amdgcn_readlane(__float_as_int(x), 63));
}
__device__ __forceinline__ float wfred_sum(float x) {
  x = x + DPPF(0.f, x, 0x111, 0xf);
  x = x + DPPF(0.f, x, 0x112, 0xf);
  x = x + DPPF(0.f, x, 0x114, 0xf);
  x = x + DPPF(0.f, x, 0x118, 0xf);
  x = x + DPPF(0.f, x, 0x142, 0xa);
  x = x + DPPF(0.f, x, 0x143, 0xc);
  return __int_as_float(__builtin_amdgcn_readlane(__float_as_int(x), 63));
}

// ---------------- split kernels: fp32 -> scaled fp16 hi/lo pairs ----------------
__global__ __launch_bounds__(256) void split_x(const float* __restrict__ x,
                                               _Float16* __restrict__ xh,
                                               _Float16* __restrict__ xl) {
  const int i = blockIdx.x * 256 + threadIdx.x;   // 4 floats per thread
  float4 v = ((const float4*)x)[i];
  const float a0 = v.x * 16.f, a1 = v.y * 16.f, a2 = v.z * 16.f, a3 = v.w * 16.f;
  const _Float16 h0 = (_Float16)a0, h1 = (_Float16)a1, h2 = (_Float16)a2, h3 = (_Float16)a3;
  half4 hv, lv;
  hv[0] = h0; hv[1] = h1; hv[2] = h2; hv[3] = h3;
  lv[0] = (_Float16)(a0 - (float)h0);
  lv[1] = (_Float16)(a1 - (float)h1);
  lv[2] = (_Float16)(a2 - (float)h2);
  lv[3] = (_Float16)(a3 - (float)h3);
  ((half4*)xh)[i] = hv;
  ((half4*)xl)[i] = lv;
}

// W[k][n] -> transposed split Wh[n][k], Wl[n][k] (scale 512), via LDS tile.
__global__ __launch_bounds__(256) void split_w4(const float* __restrict__ W0,
                                                const float* __restrict__ W1,
                                                const float* __restrict__ W2,
                                                const float* __restrict__ W3,
                                                _Float16* __restrict__ Whl_base) {
  const int z = blockIdx.z;
  const float* W = (z == 0) ? W0 : (z == 1) ? W1 : (z == 2) ? W2 : W3;
  _Float16* Wh = Whl_base + (size_t)z * 2 * (size_t)(D_ * D_);
  _Float16* Wl = Wh + (size_t)(D_ * D_);
  __shared__ float tile[64][65];
  const int t = threadIdx.x;
  const int tk = blockIdx.x & 15;
  const int tn = blockIdx.x >> 4;
  const int kr = t >> 2, ns = (t & 3) * 16;
  const float* src = W + (size_t)(tk * 64 + kr) * D_ + tn * 64 + ns;
  float4 v0 = ((const float4*)src)[0];
  float4 v1 = ((const float4*)src)[1];
  float4 v2 = ((const float4*)src)[2];
  float4 v3 = ((const float4*)src)[3];
  tile[ns + 0][kr] = v0.x;  tile[ns + 1][kr] = v0.y;  tile[ns + 2][kr] = v0.z;  tile[ns + 3][kr] = v0.w;
  tile[ns + 4][kr] = v1.x;  tile[ns + 5][kr] = v1.y;  tile[ns + 6][kr] = v1.z;  tile[ns + 7][kr] = v1.w;
  tile[ns + 8][kr] = v2.x;  tile[ns + 9][kr] = v2.y;  tile[ns + 10][kr] = v2.z; tile[ns + 11][kr] = v2.w;
  tile[ns + 12][kr] = v3.x; tile[ns + 13][kr] = v3.y; tile[ns + 14][kr] = v3.z; tile[ns + 15][kr] = v3.w;
  __syncthreads();
  const int nr = t >> 2, ks = (t & 3) * 16;
  const float* tr = &tile[nr][ks];
  half8 hv0, hv1, lv0, lv1;
#pragma unroll
  for (int i = 0; i < 8; i++) {
    const float s0 = tr[i] * 512.f;
    const float s1 = tr[i + 8] * 512.f;
    const _Float16 h0 = (_Float16)s0, h1 = (_Float16)s1;
    hv0[i] = h0; hv1[i] = h1;
    lv0[i] = (_Float16)(s0 - (float)h0);
    lv1[i] = (_Float16)(s1 - (float)h1);
  }
  _Float16* dh = Wh + (size_t)(tn * 64 + nr) * D_ + tk * 64 + ks;
  _Float16* dl = Wl + (size_t)(tn * 64 + nr) * D_ + tk * 64 + ks;
  *(half8*)dh = hv0; *(half8*)(dh + 8) = hv1;
  *(half8*)dl = lv0; *(half8*)(dl + 8) = lv1;
}

// ---------------- fp16x3 MFMA GEMM: C = (Ah+Al)(Bh+Bl)/8192 + bias ----------------
// R10: staging via async global_load_lds (16B/lane DMA). LDS layout is lane-
// linear (phys slot = t&3); the XOR swizzle lives on the per-lane GLOBAL source
// address (sl0) -- exactly the wave-uniform-dest + per-lane-source semantics.
// 2-phase loop: issue next-tile DMA, compute current, barrier (vmcnt drained).
__device__ __forceinline__ void gemm_f16x3_body(
    const _Float16* __restrict__ Ah, const _Float16* __restrict__ Al,
    const _Float16* __restrict__ Bh, const _Float16* __restrict__ Bl,
    const float* __restrict__ bias, float* __restrict__ Cf,
    _Float16* __restrict__ Ch, _Float16* __restrict__ Cl, const bool f16out) {
  __shared__ __align__(16) _Float16 sA[2][2][128][32];
  __shared__ __align__(16) _Float16 sB[2][2][128][32];
  const int t = threadIdx.x;
  const int lane = t & 63;
  const int wid = t >> 6;
  const int bm = blockIdx.y * 128;
  const int bn = blockIdx.x * 128;

  const int m0 = t >> 2, sp0 = t & 3;
  const int sl0 = sp0 ^ ((m0 >> 1) & 3);
  const int m1 = m0 + 64;
  const _Float16* gA0h = Ah + (size_t)(bm + m0) * D_ + sl0 * 8;
  const _Float16* gA1h = Ah + (size_t)(bm + m1) * D_ + sl0 * 8;
  const _Float16* gA0l = Al + (size_t)(bm + m0) * D_ + sl0 * 8;
  const _Float16* gA1l = Al + (size_t)(bm + m1) * D_ + sl0 * 8;
  const _Float16* gB0h = Bh + (size_t)(bn + m0) * D_ + sl0 * 8;
  const _Float16* gB1h = Bh + (size_t)(bn + m1) * D_ + sl0 * 8;
  const _Float16* gB0l = Bl + (size_t)(bn + m0) * D_ + sl0 * 8;
  const _Float16* gB1l = Bl + (size_t)(bn + m1) * D_ + sl0 * 8;

  char* sAb = (char*)&sA[0][0][0][0];
  char* sBb = (char*)&sB[0][0][0][0];
  const int wvb = (t >> 6) * 1024;   // wave-uniform LDS sub-base (lane*16 added by HW)

#define STAGE(pp, kk) do { \
    glds16(gA0h + (kk), sAb + (pp) * 16384 + wvb); \
    glds16(gA1h + (kk), sAb + (pp) * 16384 + 4096 + wvb); \
    glds16(gA0l + (kk), sAb + (pp) * 16384 + 8192 + wvb); \
    glds16(gA1l + (kk), sAb + (pp) * 16384 + 12288 + wvb); \
    glds16(gB0h + (kk), sBb + (pp) * 16384 + wvb); \
    glds16(gB1h + (kk), sBb + (pp) * 16384 + 4096 + wvb); \
    glds16(gB0l + (kk), sBb + (pp) * 16384 + 8192 + wvb); \
    glds16(gB1l + (kk), sBb + (pp) * 16384 + 12288 + wvb); \
  } while (0)

  STAGE(0, 0);
  __syncthreads();

  f32x4 acc[4][4];
#pragma unroll
  for (int i = 0; i < 4; i++)
#pragma unroll
    for (int j = 0; j < 4; j++) acc[i][j] = {0.f, 0.f, 0.f, 0.f};

  const int wr = wid >> 1, wc = wid & 1;
  const int l15 = lane & 15;
  const int soff = ((lane >> 4) ^ ((l15 >> 1) & 3)) * 8;

  int p = 0;
  for (int k0 = 0; k0 < 1024; k0 += 32) {
    const bool more = (k0 + 32) < 1024;
    if (more) STAGE(p ^ 1, k0 + 32);   // async DMA into other buffer
    half8 bh[4], bl[4];
#pragma unroll
    for (int ni = 0; ni < 4; ni++) {
      const int rb = wc * 64 + ni * 16 + l15;
      bh[ni] = *(const half8*)&sB[p][0][rb][soff];
      bl[ni] = *(const half8*)&sB[p][1][rb][soff];
    }
#pragma unroll
    for (int mi = 0; mi < 4; mi++) {
      const int ra = wr * 64 + mi * 16 + l15;
      const half8 ah = *(const half8*)&sA[p][0][ra][soff];
      const half8 al = *(const half8*)&sA[p][1][ra][soff];
#pragma unroll
      for (int ni = 0; ni < 4; ni++) {
        acc[mi][ni] = MFMA16(ah, bh[ni], acc[mi][ni]);
        acc[mi][ni] = MFMA16(ah, bl[ni], acc[mi][ni]);
        acc[mi][ni] = MFMA16(al, bh[ni], acc[mi][ni]);
      }
    }
    if (more) {
      __syncthreads();                 // compiler drains vmcnt before barrier
      p ^= 1;
    }
  }
#undef STAGE

  // epilogue: C row=(lane>>4)*4+reg, col=lane&15
  const float inv = 1.0f / 8192.0f;
  const int orow = bm + wr * 64 + (lane >> 4) * 4;
  const int ocol = bn + wc * 64 + l15;
#pragma unroll
  for (int ni = 0; ni < 4; ni++) {
    const int col = ocol + ni * 16;
    const float bv = bias[col];
#pragma unroll
    for (int mi = 0; mi < 4; mi++) {
      const f32x4 a = acc[mi][ni];
#pragma unroll
      for (int r = 0; r < 4; r++) {
        const size_t idx = (size_t)(orow + mi * 16 + r) * D_ + col;
        const float val = a[r] * inv + bv;
        if (f16out) {
          const float vs = val * 16.0f;            // scale 16 for attn MFMA
          const _Float16 hh = (_Float16)vs;
          Ch[idx] = hh;
          Cl[idx] = (_Float16)(vs - (float)hh);
        } else {
          Cf[idx] = val;
        }
      }
    }
  }
}

__global__ __launch_bounds__(256, 2) void gemm_qkv_f16(
    const _Float16* __restrict__ xh, const _Float16* __restrict__ xl,
    const _Float16* __restrict__ Whq, const _Float16* __restrict__ Wlq,
    const _Float16* __restrict__ Whk, const _Float16* __restrict__ Wlk,
    const _Float16* __restrict__ Whv, const _Float16* __restrict__ Wlv,
    const float* __restrict__ bq, const float* __restrict__ bk, const float* __restrict__ bv,
    _Float16* __restrict__ qh, _Float16* __restrict__ ql,
    _Float16* __restrict__ kh, _Float16* __restrict__ kl,
    float* __restrict__ vf) {
  const int z = blockIdx.z;
  const _Float16* Bh = (z == 0) ? Whq : (z == 1) ? Whk : Whv;
  const _Float16* Bl = (z == 0) ? Wlq : (z == 1) ? Wlk : Wlv;
  const float* bias = (z == 0) ? bq : (z == 1) ? bk : bv;
  if (z == 2) {
    gemm_f16x3_body(xh, xl, Bh, Bl, bias, vf, nullptr, nullptr, false);
  } else {
    _Float16* Ch = (z == 0) ? qh : kh;
    _Float16* Cl = (z == 0) ? ql : kl;
    gemm_f16x3_body(xh, xl, Bh, Bl, bias, nullptr, Ch, Cl, true);
  }
}

__global__ __launch_bounds__(256, 2) void gemm_out_f16(
    const _Float16* __restrict__ ah, const _Float16* __restrict__ al,
    const _Float16* __restrict__ bh, const _Float16* __restrict__ bl,
    const float* __restrict__ bias, float* __restrict__ C) {
  gemm_f16x3_body(ah, al, bh, bl, bias, C, nullptr, nullptr, false);
}

// ---------------- attention: MFMA QK^T + per-row top-k ----------------
// R10 = R9 (verified 309us) + pipelined gather (depth-2, two 8-wide register
// sets, one exposed latency instead of nch) + bisection 14->12 (output-
// identical: v31/v32 come from the exact descent) + cached e[16] (VGPR
// headroom exists at cap 128; values bit-identical).
#define SSWZ(row) (((row) & 7) << 2)

__global__ __launch_bounds__(512, 4) void attn_topk_mfma(
    const _Float16* __restrict__ qh, const _Float16* __restrict__ ql,
    const _Float16* __restrict__ kh, const _Float16* __restrict__ kl,
    const float* __restrict__ vf,
    _Float16* __restrict__ awh, _Float16* __restrict__ awl) {
  __shared__ float S[8][1024];   // 32 KB
  __shared__ int   cidx[8][64];  // 2 KB
  __shared__ float cfe[8][64];   // 2 KB
  const int t = threadIdx.x;
  const int lane = t & 63;
  const int w = t >> 6;              // 0..7, one q-row per wave
  // XCD swizzle: 8192 blocks; XCD k (= id%8) gets bh in [8k, 8k+8)
  const int id = blockIdx.x;
  const int wk = (id & 7) * 1024 + (id >> 3);
  const int it = wk & 127;           // i-tile of 8 rows
  const int bh = wk >> 7;            // 0..63
  const int h = bh & 15;
  const int b = bh >> 4;
  const int i0 = it * 8;
  const size_t rowbase = (size_t)b * L_;
  const int l15 = lane & 15;
  const int kgrp = lane >> 4;        // 0..3

  // ---- A-frags: rows i0 + (l15&7), duplicated over l15>=8
  half8 Ahf[2], Alf[2];
#pragma unroll
  for (int ks = 0; ks < 2; ks++) {
    const size_t off = (rowbase + i0 + (l15 & 7)) * D_ + h * DH_ + ks * 32 + kgrp * 8;
    Ahf[ks] = *(const half8*)(qh + off);
    Alf[ks] = *(const half8*)(ql + off);
  }

  // ---- QK^T: wave w covers j in [w*128, w*128+128)
  const float sscale = 1.0f / 2048.0f;  // 1/(16*16) * 1/sqrt(64)
  for (int jt = 0; jt < 8; jt++) {
    const int j0 = w * 128 + jt * 16;
    const size_t koff = (rowbase + j0 + l15) * D_ + h * DH_ + kgrp * 8;
    const half8 Bh0 = *(const half8*)(kh + koff);
    const half8 Bh1 = *(const half8*)(kh + koff + 32);
    const half8 Bl0 = *(const half8*)(kl + koff);
    const half8 Bl1 = *(const half8*)(kl + koff + 32);
    f32x4 acc = {0.f, 0.f, 0.f, 0.f};
    acc = MFMA16(Ahf[0], Bh0, acc);
    acc = MFMA16(Ahf[1], Bh1, acc);
    acc = MFMA16(Ahf[0], Bl0, acc);
    acc = MFMA16(Ahf[1], Bl1, acc);
    acc = MFMA16(Alf[0], Bh0, acc);
    acc = MFMA16(Alf[1], Bh1, acc);
    if (kgrp < 2) {
      const int srow = kgrp * 4;     // rows srow..srow+3 valid (0..7)
#pragma unroll
      for (int r = 0; r < 4; r++)
        S[srow + r][(j0 + l15) ^ SSWZ(srow + r)] = acc[r] * sscale;
    }
  }
  __syncthreads();

  // ---- selection: wave w owns row w
  const int row = w;
  const int swz = SSWZ(row);
  float sc[16];
#pragma unroll
  for (int u = 0; u < 16; u++) sc[u] = S[row][(u * 64 + lane) ^ swz];

  // ---- max (DPP)
  float mx;
  {
    float m = sc[0];
#pragma unroll
    for (int u = 1; u < 16; u++) m = fmaxf(m, sc[u]);
    mx = wfred_max(m);
  }

  // ---- bisection (window mx-16, 12 iters; exact descent below makes the
  //      iteration count output-invariant)
  float lo = mx - 16.f, hi = mx;
  for (int it2 = 0; it2 < 12; ++it2) {
    float mid = 0.5f * (lo + hi);
    int cnt = 0;
#pragma unroll
    for (int u = 0; u < 16; u++) cnt += __popcll(__ballot(sc[u] >= mid));
    if (cnt >= 32) lo = mid; else hi = mid;
  }
  int cabove = 0;
#pragma unroll
  for (int u = 0; u < 16; u++) cabove += __popcll(__ballot(sc[u] >= hi));
  float v31 = hi;
  while (cabove < 32) {
    float nx = -INFINITY;
#pragma unroll
    for (int u = 0; u < 16; u++) nx = fmaxf(nx, (sc[u] < v31) ? sc[u] : -INFINITY);
    nx = wfred_max(nx);
    int ceq = 0;
#pragma unroll
    for (int u = 0; u < 16; u++) ceq += __popcll(__ballot(sc[u] == nx));
    cabove += ceq;
    v31 = nx;
  }
  int c_eq = 0;
#pragma unroll
  for (int u = 0; u < 16; u++) c_eq += __popcll(__ballot(sc[u] == v31));
  const int c_gt = cabove - c_eq;
  const bool span = (cabove > 32);
  const int keep_eq = 32 - c_gt;
  float v32;
  if (span) {
    v32 = v31;
  } else {
    float nx = -INFINITY;
#pragma unroll
    for (int u = 0; u < 16; u++) nx = fmaxf(nx, (sc[u] < v31) ? sc[u] : -INFINITY);
    nx = wfred_max(nx);
    v32 = nx;
  }
  const float tau = 0.5f * (v31 + v32);
  const float invbeta = 166666.67f;   // 1 / 6e-6

  // ---- e cached once (bit-identical reuse); z via DPP
  float e_[16];
#pragma unroll
  for (int u = 0; u < 16; u++) e_[u] = __expf(sc[u] - mx);
  float z = 0.f;
#pragma unroll
  for (int u = 0; u < 16; u++) z += e_[u];
  z = wfred_sum(z);

  // sigmoid needed only if some score is in the transition band
  bool band = false;
  if (!span) {
    int inband = 0;
#pragma unroll
    for (int u = 0; u < 16; u++)
      inband |= (fabsf(sc[u] - tau) <= 1.81e-4f) ? 1 : 0;
    band = (__ballot(inband) != 0ull);
  }

  const float cutoff = fminf(tau - 1.8e-4f, v31);
  const float* vcol = vf + rowbase * D_ + h * DH_ + lane;
  float o;
  bool fast = false;
  if (!span) {
    // ---- compact candidates (j, fe) into LDS via ballot prefix
    int run = 0;
    float psum = 0.f;
#pragma unroll
    for (int u = 0; u < 16; u++) {
      unsigned long long m = __ballot(sc[u] >= cutoff);
      if (sc[u] >= cutoff) {
        float feu;
        if (band) {
          float arg = (sc[u] - tau) * invbeta;
          float fwv = (arg > 30.f) ? 1.f : ((arg < -30.f) ? 0.f : 1.f / (1.f + __expf(-arg)));
          feu = fwv * e_[u];
        } else {
          feu = (sc[u] > tau) ? e_[u] : 0.f;
        }
        int pos = run + (int)__popcll(m & ((1ull << lane) - 1ull));
        if (pos < 64) { cidx[row][pos] = u * 64 + lane; cfe[row][pos] = feu; }
        psum += feu;
      }
      run += (int)__popcll(m);
    }
    if (run <= 64) {
      fast = true;
      const int npad = (run + 7) & ~7;
      if (lane < npad - run) { cidx[row][run + lane] = 0; cfe[row][run + lane] = 0.f; }
      const int nch = npad >> 3;     // 4..8, wave-uniform
      auto ldc = [&](int c, int* J, float* F) {
#pragma unroll
        for (int i = 0; i < 8; i++) { J[i] = cidx[row][c * 8 + i]; F[i] = cfe[row][c * 8 + i]; }
      };
      auto ldv = [&](const int* J, float* V) {
#pragma unroll
        for (int i = 0; i < 8; i++) V[i] = vcol[(size_t)J[i] * D_];
      };
      auto fm8 = [&](const float* F, const float* V, float& a) {
#pragma unroll
        for (int i = 0; i < 8; i++) a = fmaf(F[i], V[i], a);
      };
      int jA[8], jB[8]; float fA[8], fB[8], vA[8], vB[8];
      float accv = 0.f;
      ldc(0, jA, fA); ldv(jA, vA);
      for (int c = 0; c < nch; c += 2) {
        if (c + 1 < nch) { ldc(c + 1, jB, fB); ldv(jB, vB); }
        fm8(fA, vA, accv);
        if (c + 2 < nch) { ldc(c + 2, jA, fA); ldv(jA, vA); }
        if (c + 1 < nch) fm8(fB, vB, accv);
      }
      const float Ssum = wfred_sum(psum);
      o = accv / (Ssum + 1e-8f * z);
    }
  }
  if (!fast) {
    // ---- exact original serial path (span ties / candidate overflow)
    float Ssum = 0.f, acc = 0.f;
    int eq_seen = 0;
    for (int u = 0; u < 16; ++u) {
      unsigned long long mask = __ballot(sc[u] >= cutoff);
      while (mask) {
        int l2 = (int)__builtin_ctzll(mask);
        mask &= mask - 1;
        float s_ = __shfl(sc[u], l2, 64);
        float e2 = __expf(s_ - mx);
        float f_;
        if (span) {
          if (s_ > v31) f_ = 1.f;
          else if (s_ == v31) { f_ = (eq_seen < keep_eq) ? 1.f : 0.f; ++eq_seen; }
          else f_ = 0.f;
        } else {
          float arg = (s_ - tau) * invbeta;
          f_ = (arg > 30.f) ? 1.f : ((arg < -30.f) ? 0.f : 1.f / (1.f + __expf(-arg)));
        }
        float fe_ = f_ * e2;
        Ssum += fe_;
        acc = fmaf(fe_, vcol[(size_t)(u * 64 + l2) * D_], acc);
      }
    }
    o = acc / (Ssum + 1e-8f * z);
  }

  const float os = o * 16.0f;                  // scale 16 for the f16x3 out-GEMM
  const _Float16 oh = (_Float16)os;
  const size_t oidx = (rowbase + i0 + row) * D_ + h * DH_ + lane;
  awh[oidx] = oh;
  awl[oidx] = (_Float16)(os - (float)oh);
}

extern "C" void kernel_launch(void* const* d_in, const int* in_sizes, int n_in,
                              void* d_out, int out_size, void* d_ws, size_t ws_size,
                              hipStream_t stream) {
  const float* x  = (const float*)d_in[0];
  const float* Wq = (const float*)d_in[1];
  const float* bq = (const float*)d_in[2];
  const float* Wk = (const float*)d_in[3];
  const float* bk = (const float*)d_in[4];
  const float* Wv = (const float*)d_in[5];
  const float* bv = (const float*)d_in[6];
  const float* Wo = (const float*)d_in[7];
  const float* bo = (const float*)d_in[8];
  float* out = (float*)d_out;

  const size_t MD = (size_t)M_ * D_;   // 4M elements
  const size_t WD = (size_t)D_ * D_;   // 1M elements
  float* slot0 = (float*)d_ws;
  float* slot1 = slot0 + MD;
  float* vf    = slot1 + MD;
  float* slot3 = vf + MD;
  float* slot4 = slot3 + MD;

  _Float16* qh = (_Float16*)slot0;  _Float16* ql = qh + MD;
  _Float16* kh = (_Float16*)slot1;  _Float16* kl = kh + MD;
  _Float16* xh = (_Float16*)slot3;  _Float16* xl = xh + MD;
  _Float16* awh = xh;               // alias: xh/xl dead after gemm_qkv
  _Float16* awl = xl;
  _Float16* Wsplit = (_Float16*)slot4;   // 8 x WD f16: Whq Wlq Whk Wlk Whv Wlv Who Wlo
  _Float16* Whq = Wsplit;
  _Float16* Wlq = Whq + WD;
  _Float16* Whk = Wlq + WD;
  _Float16* Wlk = Whk + WD;
  _Float16* Whv = Wlk + WD;
  _Float16* Wlv = Whv + WD;
  _Float16* Who = Wlv + WD;
  _Float16* Wlo = Who + WD;

  dim3 b256(256);
  hipLaunchKernelGGL(split_x, dim3(4096), b256, 0, stream, x, xh, xl);
  hipLaunchKernelGGL(split_w4, dim3(256, 1, 4), b256, 0, stream, Wq, Wk, Wv, Wo, Wsplit);
  hipLaunchKernelGGL(gemm_qkv_f16, dim3(8, 32, 3), b256, 0, stream,
                     xh, xl, Whq, Wlq, Whk, Wlk, Whv, Wlv, bq, bk, bv,
                     qh, ql, kh, kl, vf);
  hipLaunchKernelGGL(attn_topk_mfma, dim3(8192), dim3(512), 0, stream,
                     qh, ql, kh, kl, vf, awh, awl);
  hipLaunchKernelGGL(gemm_out_f16, dim3(8, 32), b256, 0, stream,
                     awh, awl, Who, Wlo, bo, out);
}